// Round 10
// baseline (277.276 us; speedup 1.0000x reference)
//
#include <hip/hip_runtime.h>

#define NN 4096
#define EE 262144
#define INF_ 64
#define HH 128
#define HEADS 4
#define DH 32
#define LL 2
#define NH (NN * HH)
#define KSPLIT 8
#define L2E 1.4426950408889634f

typedef unsigned short u16;
typedef unsigned int u32;
using bf16x8 = __attribute__((ext_vector_type(8))) short;
using f32x4 = __attribute__((ext_vector_type(4))) float;

__device__ __forceinline__ float bf2f(u16 v) { return __uint_as_float(((u32)v) << 16); }
__device__ __forceinline__ u16 f2bf(float f) {
    u32 u = __float_as_uint(f);
    u32 r = (u + 0x7fffu + ((u >> 16) & 1u)) >> 16;
    return (u16)r;
}
__device__ __forceinline__ u32 encf(float f) {
    u32 b = __float_as_uint(f);
    return (b & 0x80000000u) ? ~b : (b | 0x80000000u);
}
__device__ __forceinline__ float decf(u32 u) {
    u32 b = (u & 0x80000000u) ? (u & 0x7fffffffu) : ~u;
    return __uint_as_float(b);
}

// ---------------- dtype detect + zero-init (cnt, gmax) ----------------
__global__ __launch_bounds__(256) void k_detect(const u16* __restrict__ x, int* __restrict__ flag,
                                                int* __restrict__ cnt, u32* __restrict__ gmax) {
    int t = threadIdx.x;
    for (int i = t; i < NN; i += 256) cnt[i] = 0;
    if (t < 16) gmax[t] = 0;
    __shared__ int cs[256];
    u16 v = x[2 * t];
    int e = (v >> 7) & 0xFF;
    cs[t] = (e >= 100 && e <= 140) ? 1 : 0;
    __syncthreads();
    for (int s = 128; s > 0; s >>= 1) {
        if (t < s) cs[t] += cs[t + s];
        __syncthreads();
    }
    if (t == 0) *flag = (cs[0] >= 128) ? 1 : 0;
}

// ---------------- merged param conversion + edge histogram ----------------
#define MAXSEG 16
struct SegF { const void* src[MAXSEG]; int dst[MAXSEG]; int n[MAXSEG]; int cnt; };
struct SegB { const void* src[8]; u16* dst[8]; u16* dst2[8]; int n[8]; int cnt; };
// blocks [0,96): cvtf (8 per seg x 12), [96,992): cvtb (128 per seg x 7), [992,2016): hist
__global__ __launch_bounds__(256) void k_prep(SegF SF, float* __restrict__ W, SegB SB,
                                              const int* __restrict__ flag,
                                              const int* __restrict__ dst, int* __restrict__ cnt) {
    int bid = blockIdx.x, t = threadIdx.x;
    if (bid < 96) {
        int seg = bid >> 3, bx = bid & 7;
        if (seg >= SF.cnt) return;
        int n = SF.n[seg];
        float* d = W + SF.dst[seg];
        const void* s = SF.src[seg];
        int f = *flag;
        for (int i = bx * 256 + t; i < n; i += 8 * 256)
            d[i] = f ? bf2f(((const u16*)s)[i]) : ((const float*)s)[i];
    } else if (bid < 992) {
        int b2 = bid - 96;
        int seg = b2 >> 7, bx = b2 & 127;
        if (seg >= SB.cnt) return;
        int f = *flag;
        u16* d = SB.dst[seg];
        u16* d2 = SB.dst2[seg];
        if (f && !d2) return;   // weights already bf16 in d_in
        int n = SB.n[seg];
        const void* s = SB.src[seg];
        for (int i = bx * 256 + t; i < n; i += 128 * 256) {
            if (d2) {
                float v = f ? bf2f(((const u16*)s)[i]) : ((const float*)s)[i];
                u16 h = f2bf(v);
                d[i] = h;
                d2[i] = f2bf(v - bf2f(h));
            } else {
                d[i] = f2bf(((const float*)s)[i]);
            }
        }
    } else {
        int e = (bid - 992) * 256 + t;
        if (e < EE) atomicAdd(&cnt[dst[e]], 1);
    }
}

// ---------------- generic MFMA GEMM, M-tile 32 / J-tile 64 (acc[4]) ----------------
// blockIdx.y >= jtiles: CSR scan rider block (x==0 only; runs after k_prep's hist).
__global__ __launch_bounds__(128) void k_mgemm(const u16* __restrict__ Ahi, const u16* __restrict__ Alo,
                                               const u16* __restrict__ Wc, const u16* __restrict__ Wd,
                                               const int* __restrict__ flag,
                                               const float* __restrict__ bias,
                                               float* __restrict__ outf, u16* __restrict__ outb16,
                                               u16* __restrict__ outhi, u16* __restrict__ outlo,
                                               int K, int J, int relu, int jtiles,
                                               const int* __restrict__ scnt, int* __restrict__ srowstart,
                                               int* __restrict__ scursor) {
    __shared__ int part[128];
    if ((int)blockIdx.y >= jtiles) {
        // ---- 128-thread CSR scan (NN = 128 x 32) ----
        if (blockIdx.x != 0 || scnt == nullptr) return;
        int t = threadIdx.x;
        int loc[32];
        int s = 0;
#pragma unroll
        for (int i = 0; i < 32; ++i) { loc[i] = s; s += scnt[t * 32 + i]; }
        part[t] = s;
        __syncthreads();
        for (int off = 1; off < 128; off <<= 1) {
            int v = part[t];
            int a = (t >= off) ? part[t - off] : 0;
            __syncthreads();
            part[t] = v + a;
            __syncthreads();
        }
        int base = (t == 0) ? 0 : part[t - 1];
#pragma unroll
        for (int i = 0; i < 32; ++i) {
            srowstart[t * 32 + i] = base + loc[i];
            scursor[t * 32 + i] = base + loc[i];
        }
        return;
    }
    const u16* Wb = (*flag) ? Wd : Wc;
    int wave = threadIdx.x >> 6, lane = threadIdx.x & 63;
    int grp = lane >> 4, lcol = lane & 15;
    int m0 = blockIdx.x * 32 + wave * 16;
    int j0 = blockIdx.y * 64;
    f32x4 acc[4];
#pragma unroll
    for (int s = 0; s < 4; ++s) acc[s] = (f32x4){0.f, 0.f, 0.f, 0.f};
    const u16* ah = Ahi + (size_t)(m0 + lcol) * K + grp * 8;
    const u16* al = Alo + (size_t)(m0 + lcol) * K + grp * 8;
    const u16* wb = Wb + (size_t)(j0 + lcol) * K + grp * 8;
    for (int k = 0; k < K; k += 32) {
        bf16x8 va = *(const bf16x8*)(ah + k);
        bf16x8 vl = *(const bf16x8*)(al + k);
#pragma unroll
        for (int s = 0; s < 4; ++s) {
            bf16x8 vw = *(const bf16x8*)(wb + (size_t)s * 16 * K + k);
            acc[s] = __builtin_amdgcn_mfma_f32_16x16x32_bf16(va, vw, acc[s], 0, 0, 0);
            acc[s] = __builtin_amdgcn_mfma_f32_16x16x32_bf16(vl, vw, acc[s], 0, 0, 0);
        }
    }
#pragma unroll
    for (int s = 0; s < 4; ++s) {
        int col = j0 + s * 16 + lcol;
        float bs = bias ? bias[col] : 0.f;
#pragma unroll
        for (int r = 0; r < 4; ++r) {
            float v = acc[s][r] + bs;
            if (relu) v = fmaxf(v, 0.f);
            size_t idx = (size_t)(m0 + grp * 4 + r) * J + col;
            if (outf) outf[idx] = v;
            if (outb16) outb16[idx] = f2bf(v);
            if (outhi) {
                u16 hv = f2bf(v);
                outhi[idx] = hv;
                outlo[idx] = f2bf(v - bf2f(hv));
            }
        }
    }
}

// ---------------- fused GAT-xp + QKV GEMM, J-tile 64 (+ scatter rider blocks y>=8) ----------------
__global__ __launch_bounds__(128) void k_gemm_gq(const u16* __restrict__ Ahi, const u16* __restrict__ Alo,
                                                 const u16* __restrict__ wgatc, const u16* __restrict__ wgatd,
                                                 const u16* __restrict__ wqkvc, const u16* __restrict__ wqkvd,
                                                 const int* __restrict__ flag,
                                                 const float* __restrict__ bqkv,
                                                 u16* __restrict__ xpb, u16* __restrict__ qkvb,
                                                 const int* __restrict__ esrc_src, const int* __restrict__ esrc_dst,
                                                 int* __restrict__ cursor, int* __restrict__ esrc) {
    if (blockIdx.y >= 8) {
        // ---- CSR scatter rider (layer 0 only; 256 blocks x 128 thr) ----
        int b = (blockIdx.y - 8) * 128 + blockIdx.x;
        for (int e = b * 128 + threadIdx.x; e < EE; e += 32768) {
            int d = esrc_dst[e];
            int p = atomicAdd(&cursor[d], 1);
            esrc[p] = esrc_src[e];
        }
        return;
    }
    int wave = threadIdx.x >> 6, lane = threadIdx.x & 63;
    int grp = lane >> 4, lcol = lane & 15;
    int m0 = blockIdx.x * 32 + wave * 16;
    int jb = blockIdx.y;
    int j0 = jb * 64;
    int f = *flag;
    const u16* wgat = f ? wgatd : wgatc;
    const u16* wqkv = f ? wqkvd : wqkvc;
    const u16* Wb = (jb < 2) ? (wgat + (size_t)j0 * HH) : (wqkv + (size_t)(j0 - 128) * HH);
    f32x4 acc[4];
#pragma unroll
    for (int s = 0; s < 4; ++s) acc[s] = (f32x4){0.f, 0.f, 0.f, 0.f};
    const u16* ah = Ahi + (size_t)(m0 + lcol) * HH + grp * 8;
    const u16* al = Alo + (size_t)(m0 + lcol) * HH + grp * 8;
    const u16* wb = Wb + (size_t)lcol * HH + grp * 8;
    for (int k = 0; k < HH; k += 32) {
        bf16x8 va = *(const bf16x8*)(ah + k);
        bf16x8 vl = *(const bf16x8*)(al + k);
#pragma unroll
        for (int s = 0; s < 4; ++s) {
            bf16x8 vw = *(const bf16x8*)(wb + (size_t)s * 16 * HH + k);
            acc[s] = __builtin_amdgcn_mfma_f32_16x16x32_bf16(va, vw, acc[s], 0, 0, 0);
            acc[s] = __builtin_amdgcn_mfma_f32_16x16x32_bf16(vl, vw, acc[s], 0, 0, 0);
        }
    }
    if (jb < 2) {
#pragma unroll
        for (int s = 0; s < 4; ++s) {
            int col = j0 + s * 16 + lcol;
#pragma unroll
            for (int r = 0; r < 4; ++r)
                xpb[(size_t)(m0 + grp * 4 + r) * HH + col] = f2bf(acc[s][r]);
        }
    } else {
#pragma unroll
        for (int s = 0; s < 4; ++s) {
            int colq = j0 - 128 + s * 16 + lcol;
            float bs = bqkv[colq];
#pragma unroll
            for (int r = 0; r < 4; ++r)
                qkvb[(size_t)(m0 + grp * 4 + r) * 384 + colq] = f2bf(acc[s][r] + bs);
        }
    }
}

// ---------------- fused w_o + combine + MLP (+ optional output projection) ----------------
// Block = 16 rows, 256 threads (4 waves). Phase A: wo GEMM + combine -> LDS. Phase B: w1
// from LDS -> hidden in LDS. Phase C: w2 K=256 from LDS + final epilogue (stashes final h
// into Of). If yout != nullptr (last layer): 16-lane shfl-dot output projection from Of.
__global__ __launch_bounds__(256) void k_womlp(const u16* __restrict__ Ahi, const u16* __restrict__ Alo,
                                               const u16* __restrict__ Woc, const u16* __restrict__ Wod,
                                               const u16* __restrict__ W1c, const u16* __restrict__ W1d,
                                               const u16* __restrict__ W2c, const u16* __restrict__ W2d,
                                               const int* __restrict__ flag,
                                               const float* __restrict__ bo, const float* __restrict__ b1,
                                               const float* __restrict__ b2,
                                               const float* __restrict__ gatb, const float* __restrict__ bgat,
                                               const float* __restrict__ gam, const float* __restrict__ bet,
                                               const float* __restrict__ gam2, const float* __restrict__ bet2,
                                               float* __restrict__ hbuf, u16* __restrict__ hhi,
                                               u16* __restrict__ hlo,
                                               const float* __restrict__ wout, const float* __restrict__ bout,
                                               void* __restrict__ yout) {
    __shared__ float Of[16][132];                 // 8448 B (528 B row stride)
    __shared__ u16 A2hi[16][136], A2lo[16][136];  // 4352 B each (272 B stride, 16B-aligned)
    __shared__ u16 Hhi[16][264], Hlo[16][264];    // 8448 B each
    int f = *flag;
    const u16* Wo = f ? Wod : Woc;
    const u16* W1 = f ? W1d : W1c;
    const u16* W2 = f ? W2d : W2c;
    int wave = threadIdx.x >> 6, lane = threadIdx.x & 63;
    int grp = lane >> 4, lcol = lane & 15;
    int m0 = blockIdx.x * 16;
    float rs = rsqrtf(1.00001f);

    // ---- phase A: wo GEMM (K=128) + combine epilogue -> LDS ----
    {
        int j0 = wave * 32;
        f32x4 acc[2];
#pragma unroll
        for (int s = 0; s < 2; ++s) acc[s] = (f32x4){0.f, 0.f, 0.f, 0.f};
        const u16* ah = Ahi + (size_t)(m0 + lcol) * HH + grp * 8;
        const u16* al = Alo + (size_t)(m0 + lcol) * HH + grp * 8;
        const u16* wb = Wo + (size_t)(j0 + lcol) * HH + grp * 8;
#pragma unroll
        for (int k = 0; k < HH; k += 32) {
            bf16x8 va = *(const bf16x8*)(ah + k);
            bf16x8 vl = *(const bf16x8*)(al + k);
#pragma unroll
            for (int s = 0; s < 2; ++s) {
                bf16x8 vw = *(const bf16x8*)(wb + (size_t)s * 16 * HH + k);
                acc[s] = __builtin_amdgcn_mfma_f32_16x16x32_bf16(va, vw, acc[s], 0, 0, 0);
                acc[s] = __builtin_amdgcn_mfma_f32_16x16x32_bf16(vl, vw, acc[s], 0, 0, 0);
            }
        }
#pragma unroll
        for (int s = 0; s < 2; ++s) {
            int col = j0 + s * 16 + lcol;
            float bs = bo[col];
            float g0 = gam[col] * rs, b0 = bet[col];
            float g1 = gam[HH + col] * rs, bb1 = bet[HH + col];
            float bg = bgat[col];
#pragma unroll
            for (int r = 0; r < 4; ++r) {
                int row = grp * 4 + r;
                size_t idx = (size_t)(m0 + row) * HH + col;
                float proj = acc[s][r] + bs;
                float hv = hbuf[idx];
                float hl = g0 * (gatb[idx] + bg + hv) + b0;
                float ha = g1 * (proj + hv) + bb1;
                float v = hl + ha;
                Of[row][col] = v;
                u16 hb = f2bf(v);
                A2hi[row][col] = hb;
                A2lo[row][col] = f2bf(v - bf2f(hb));
            }
        }
    }
    __syncthreads();
    // ---- phase B: w1 GEMM (K=128 from LDS) -> hidden hi/lo in LDS ----
    {
        int j0 = wave * 64;
        f32x4 acc[4];
#pragma unroll
        for (int s = 0; s < 4; ++s) acc[s] = (f32x4){0.f, 0.f, 0.f, 0.f};
        const u16* wb = W1 + (size_t)(j0 + lcol) * HH + grp * 8;
#pragma unroll
        for (int k = 0; k < HH; k += 32) {
            bf16x8 va = *(const bf16x8*)(&A2hi[lcol][k + grp * 8]);
            bf16x8 vl = *(const bf16x8*)(&A2lo[lcol][k + grp * 8]);
#pragma unroll
            for (int s = 0; s < 4; ++s) {
                bf16x8 vw = *(const bf16x8*)(wb + (size_t)s * 16 * HH + k);
                acc[s] = __builtin_amdgcn_mfma_f32_16x16x32_bf16(va, vw, acc[s], 0, 0, 0);
                acc[s] = __builtin_amdgcn_mfma_f32_16x16x32_bf16(vl, vw, acc[s], 0, 0, 0);
            }
        }
#pragma unroll
        for (int s = 0; s < 4; ++s) {
            int col = j0 + s * 16 + lcol;
            float bs = b1[col];
#pragma unroll
            for (int r = 0; r < 4; ++r) {
                float v = fmaxf(acc[s][r] + bs, 0.f);
                int row = grp * 4 + r;
                u16 hv = f2bf(v);
                Hhi[row][col] = hv;
                Hlo[row][col] = f2bf(v - bf2f(hv));
            }
        }
    }
    __syncthreads();
    // ---- phase C: w2 GEMM (K=256 from LDS) + final epilogue ----
    {
        int j0 = wave * 32;
        f32x4 acc[2];
#pragma unroll
        for (int s = 0; s < 2; ++s) acc[s] = (f32x4){0.f, 0.f, 0.f, 0.f};
        const u16* wb = W2 + (size_t)(j0 + lcol) * 256 + grp * 8;
#pragma unroll
        for (int k = 0; k < 256; k += 32) {
            bf16x8 va = *(const bf16x8*)(&Hhi[lcol][k + grp * 8]);
            bf16x8 vl = *(const bf16x8*)(&Hlo[lcol][k + grp * 8]);
#pragma unroll
            for (int s = 0; s < 2; ++s) {
                bf16x8 vw = *(const bf16x8*)(wb + (size_t)s * 16 * 256 + k);
                acc[s] = __builtin_amdgcn_mfma_f32_16x16x32_bf16(va, vw, acc[s], 0, 0, 0);
                acc[s] = __builtin_amdgcn_mfma_f32_16x16x32_bf16(vl, vw, acc[s], 0, 0, 0);
            }
        }
#pragma unroll
        for (int s = 0; s < 2; ++s) {
            int col = j0 + s * 16 + lcol;
            float bs = b2[col];
            float g2 = gam2[col] * rs, bb2 = bet2[col];
#pragma unroll
            for (int r = 0; r < 4; ++r) {
                int row = grp * 4 + r;
                size_t idx = (size_t)(m0 + row) * HH + col;
                float mlpo = acc[s][r] + bs;
                float o2 = g2 * (Of[row][col] + mlpo) + bb2;
                float v = fmaxf(o2 + hbuf[idx], 0.f);
                hbuf[idx] = v;
                Of[row][col] = v;  // stash final h for output projection
                u16 hb = f2bf(v);
                hhi[idx] = hb;
                hlo[idx] = f2bf(v - bf2f(hb));
            }
        }
    }
    // ---- optional output projection (last layer): y[row] = h . w_out^T + b_out ----
    if (yout) {
        __syncthreads();
        int row = threadIdx.x >> 4, sub = threadIdx.x & 15;
        float a0 = 0.f, a1 = 0.f;
#pragma unroll
        for (int k8 = 0; k8 < 8; ++k8) {
            int k = sub * 8 + k8;
            float hv = Of[row][k];
            a0 += hv * wout[k];
            a1 += hv * wout[HH + k];
        }
#pragma unroll
        for (int off = 1; off < 16; off <<= 1) {
            a0 += __shfl_xor(a0, off);
            a1 += __shfl_xor(a1, off);
        }
        if (sub == 0) {
            int n = m0 + row;
            float o0 = a0 + bout[0], o1 = a1 + bout[1];
            if (f) {
                u16* y = (u16*)yout;
                y[n * 2 + 0] = f2bf(o0);
                y[n * 2 + 1] = f2bf(o1);
            } else {
                float* y = (float*)yout;
                y[n * 2 + 0] = o0;
                y[n * 2 + 1] = o1;
            }
        }
    }
}

// ---------------- merged MHA flash split + attlog (blocks >= 1024) ----------------
// split part: 32-key P chunks (LDS 19 KB -> 8 blocks/CU), kappa32 V layout. KSPLIT=8: NT=8.
__global__ __launch_bounds__(256) void k_splitlog(const u16* __restrict__ qkvb,
                                                  float* __restrict__ PM, float* __restrict__ PL,
                                                  u16* __restrict__ PO,
                                                  const u16* __restrict__ xpb,
                                                  const float* __restrict__ asrc,
                                                  const float* __restrict__ adst,
                                                  float* __restrict__ als, float* __restrict__ ald,
                                                  u32* __restrict__ gmax) {
    __shared__ __align__(16) u16 Klds[64][40];     // 5120 B
    __shared__ __align__(16) u32 Vlds[32][40];     // 5120 B
    __shared__ __align__(16) u16 Plds[4][32][36];  // 9216 B

    if (blockIdx.x >= 32 * HEADS * KSPLIT) {
        // ---- attlog path (64 blocks) ----
        float* red = (float*)&Klds[0][0];  // 1 KB alias
        int t = (blockIdx.x - 32 * HEADS * KSPLIT) * 256 + threadIdx.x;
        int n = t >> 2, hh = t & 3;
        const u16* xr = xpb + (size_t)n * HH + hh * DH;
        float s1 = 0.f, s2 = 0.f;
#pragma unroll
        for (int d = 0; d < DH; ++d) {
            float v = bf2f(xr[d]);
            s1 += v * asrc[hh * DH + d];
            s2 += v * adst[hh * DH + d];
        }
        als[t] = s1;
        ald[t] = s2;
        int lt = threadIdx.x;
        red[lt] = s1;
        __syncthreads();
        for (int off = 128; off >= 4; off >>= 1) {
            if (lt < off) red[lt] = fmaxf(red[lt], red[lt + off]);
            __syncthreads();
        }
        if (lt < 4) atomicMax(&gmax[lt], encf(red[lt]));
        __syncthreads();
        red[lt] = s2;
        __syncthreads();
        for (int off = 128; off >= 4; off >>= 1) {
            if (lt < off) red[lt] = fmaxf(red[lt], red[lt + off]);
            __syncthreads();
        }
        if (lt < 4) atomicMax(&gmax[4 + lt], encf(red[lt]));
        return;
    }

    // ---- flash split path (32*HEADS*KSPLIT blocks) ----
    const float C1 = 0.17677669529663687f * L2E;
    int head = blockIdx.x & 3;
    int qt = (blockIdx.x >> 2) & 31;
    int ks = blockIdx.x >> 7;
    int tid = threadIdx.x;
    int wave = tid >> 6, lane = tid & 63;
    int grp = lane >> 4, lcol = lane & 15;

    int qrow0 = qt * 128 + wave * 32;
    bf16x8 aQ0 = *(const bf16x8*)(qkvb + (size_t)(qrow0 + lcol) * 384 + head * 32 + grp * 8);
    bf16x8 aQ1 = *(const bf16x8*)(qkvb + (size_t)(qrow0 + 16 + lcol) * 384 + head * 32 + grp * 8);

    short onev = (lcol == 0) ? (short)0x3F80 : (short)0;
    bf16x8 bOne = {onev, onev, onev, onev, onev, onev, onev, onev};

    f32x4 oc00 = {0.f, 0.f, 0.f, 0.f}, oc01 = {0.f, 0.f, 0.f, 0.f};
    f32x4 oc10 = {0.f, 0.f, 0.f, 0.f}, oc11 = {0.f, 0.f, 0.f, 0.f};
    f32x4 ol0 = {0.f, 0.f, 0.f, 0.f}, ol1 = {0.f, 0.f, 0.f, 0.f};
    float msh = -INFINITY;

    int isK = (tid < 128);
    int st = tid & 127;
    int skey = st >> 1, shalf = (st & 1) * 16;
    int vj = st & 15, vc = (st >> 4) & 1, dgrp = st >> 5;
    const u16* kptr = qkvb + 128 + head * 32 + shalf;
    const u16* vptr = qkvb + 256 + head * 32 + dgrp * 8;
    int vk0 = vc * 32 + vj;
    int vk1 = vc * 32 + 16 + vj;

    int kt0 = ks * (NN / KSPLIT);
    bf16x8 r0, r1;
    if (isK) {
        r0 = *(const bf16x8*)(kptr + (size_t)(kt0 + skey) * 384);
        r1 = *(const bf16x8*)(kptr + (size_t)(kt0 + skey) * 384 + 8);
    } else {
        r0 = *(const bf16x8*)(vptr + (size_t)(kt0 + vk0) * 384);
        r1 = *(const bf16x8*)(vptr + (size_t)(kt0 + vk1) * 384);
    }

    const int NT = (NN / KSPLIT) / 64;
    for (int t = 0; t < NT; ++t) {
        if (isK) {
            *(bf16x8*)(&Klds[skey][shalf]) = r0;
            *(bf16x8*)(&Klds[skey][shalf + 8]) = r1;
        } else {
#pragma unroll
            for (int j = 0; j < 8; ++j)
                Vlds[dgrp * 8 + j][vc * 20 + vj] = (u32)(u16)r0[j] | ((u32)(u16)r1[j] << 16);
        }
        __syncthreads();
        if (t + 1 < NT) {
            int kn = kt0 + (t + 1) * 64;
            if (isK) {
                r0 = *(const bf16x8*)(kptr + (size_t)(kn + skey) * 384);
                r1 = *(const bf16x8*)(kptr + (size_t)(kn + skey) * 384 + 8);
            } else {
                r0 = *(const bf16x8*)(vptr + (size_t)(kn + vk0) * 384);
                r1 = *(const bf16x8*)(vptr + (size_t)(kn + vk1) * 384);
            }
        }
        f32x4 sc0[4], sc1[4];
        f32x4 zero = {0.f, 0.f, 0.f, 0.f};
        __builtin_amdgcn_s_setprio(1);
#pragma unroll
        for (int s = 0; s < 4; ++s) {
            bf16x8 bK = *(const bf16x8*)(&Klds[s * 16 + lcol][grp * 8]);
            sc0[s] = __builtin_amdgcn_mfma_f32_16x16x32_bf16(aQ0, bK, zero, 0, 0, 0);
            sc1[s] = __builtin_amdgcn_mfma_f32_16x16x32_bf16(aQ1, bK, zero, 0, 0, 0);
        }
        __builtin_amdgcn_s_setprio(0);
        float mymax = sc0[0][0];
#pragma unroll
        for (int s = 0; s < 4; ++s)
#pragma unroll
            for (int r = 0; r < 4; ++r) {
                mymax = fmaxf(mymax, sc0[s][r]);
                mymax = fmaxf(mymax, sc1[s][r]);
            }
        mymax = fmaxf(mymax, __shfl_xor(mymax, 1));
        mymax = fmaxf(mymax, __shfl_xor(mymax, 2));
        mymax = fmaxf(mymax, __shfl_xor(mymax, 4));
        mymax = fmaxf(mymax, __shfl_xor(mymax, 8));
        float mnew = fmaxf(msh, mymax * C1);
        float cc = __builtin_exp2f(msh - mnew);
        msh = mnew;
        oc00 *= cc; oc01 *= cc; ol0 *= cc;
        oc10 *= cc; oc11 *= cc; ol1 *= cc;
#pragma unroll
        for (int c2 = 0; c2 < 2; ++c2) {
#pragma unroll
            for (int r = 0; r < 4; ++r) {
                float p0 = __builtin_exp2f(__builtin_fmaf(sc0[2 * c2][r], C1, -mnew));
                float p1 = __builtin_exp2f(__builtin_fmaf(sc0[2 * c2 + 1][r], C1, -mnew));
                *(u32*)(&Plds[wave][grp * 4 + r][2 * lcol]) =
                    __builtin_amdgcn_perm(__float_as_uint(p1), __float_as_uint(p0), 0x07060302u);
                float q0 = __builtin_exp2f(__builtin_fmaf(sc1[2 * c2][r], C1, -mnew));
                float q1 = __builtin_exp2f(__builtin_fmaf(sc1[2 * c2 + 1][r], C1, -mnew));
                *(u32*)(&Plds[wave][16 + grp * 4 + r][2 * lcol]) =
                    __builtin_amdgcn_perm(__float_as_uint(q1), __float_as_uint(q0), 0x07060302u);
            }
            bf16x8 aP0 = *(const bf16x8*)(&Plds[wave][lcol][grp * 8]);
            bf16x8 aP1 = *(const bf16x8*)(&Plds[wave][16 + lcol][grp * 8]);
            bf16x8 bV0 = *(const bf16x8*)(&Vlds[lcol][c2 * 20 + grp * 4]);
            bf16x8 bV1 = *(const bf16x8*)(&Vlds[16 + lcol][c2 * 20 + grp * 4]);
            __builtin_amdgcn_s_setprio(1);
            oc00 = __builtin_amdgcn_mfma_f32_16x16x32_bf16(aP0, bV0, oc00, 0, 0, 0);
            oc01 = __builtin_amdgcn_mfma_f32_16x16x32_bf16(aP0, bV1, oc01, 0, 0, 0);
            ol0 = __builtin_amdgcn_mfma_f32_16x16x32_bf16(aP0, bOne, ol0, 0, 0, 0);
            oc10 = __builtin_amdgcn_mfma_f32_16x16x32_bf16(aP1, bV0, oc10, 0, 0, 0);
            oc11 = __builtin_amdgcn_mfma_f32_16x16x32_bf16(aP1, bV1, oc11, 0, 0, 0);
            ol1 = __builtin_amdgcn_mfma_f32_16x16x32_bf16(aP1, bOne, ol1, 0, 0, 0);
            __builtin_amdgcn_s_setprio(0);
        }
        __syncthreads();
    }
#pragma unroll
    for (int r = 0; r < 4; ++r) {
        int row0 = qrow0 + grp * 4 + r;
        size_t b0 = ((size_t)row0 * HEADS + head) * KSPLIT + ks;
        PO[b0 * 32 + lcol] = f2bf(oc00[r]);
        PO[b0 * 32 + 16 + lcol] = f2bf(oc01[r]);
        int row1 = row0 + 16;
        size_t b1 = ((size_t)row1 * HEADS + head) * KSPLIT + ks;
        PO[b1 * 32 + lcol] = f2bf(oc10[r]);
        PO[b1 * 32 + 16 + lcol] = f2bf(oc11[r]);
        if (lcol == 0) {
            PM[b0] = msh;
            PL[b0] = ol0[r];
            PM[b1] = msh;
            PL[b1] = ol1[r];
        }
    }
}

// ---------------- merged GAT node pass + MHA combine (blocks >= NN) ----------------
// GAT PV gather: u32 loads (2 dims/lane), 128 threads = 2 edges/step (halved load count).
#define GCHUNK 256
__global__ __launch_bounds__(128) void k_gatcomb(const int* __restrict__ esrc, const int* __restrict__ rowstart,
                                                 const int* __restrict__ cnt, const float* __restrict__ als,
                                                 const float* __restrict__ ald, const u16* __restrict__ xpb,
                                                 float* __restrict__ gatout, const u32* __restrict__ gmax,
                                                 const float* __restrict__ PM, const float* __restrict__ PL,
                                                 const u16* __restrict__ PO, u16* __restrict__ atthi,
                                                 u16* __restrict__ attlo) {
    __shared__ float red[512];
    __shared__ float elds[GCHUNK * 4];
    __shared__ int slds[GCHUNK];
    int t = threadIdx.x;

    if (blockIdx.x >= NN) {
        // ---- MHA combine path: one row per block (KSPLIT=8: 32 wn entries) ----
        int n2 = blockIdx.x - NN;
        float* wn = red;  // 32 floats alias
        if (t < 4 * KSPLIT) {
            int head = t >> 3, ks = t & 7;
            size_t b = ((size_t)n2 * HEADS + head) * KSPLIT + ks;
            float pm = PM[b];
            float m = pm;
#pragma unroll
            for (int off = 1; off < KSPLIT; off <<= 1) m = fmaxf(m, __shfl_xor(m, off));
            float w = __builtin_exp2f(pm - m);
            float lw = PL[b] * w;
#pragma unroll
            for (int off = 1; off < KSPLIT; off <<= 1) lw += __shfl_xor(lw, off);
            wn[t] = w / lw;
        }
        __syncthreads();
        int head = t >> 5, dim = t & 31;
        size_t b0 = ((size_t)n2 * HEADS + head) * KSPLIT;
        float o = 0.f;
#pragma unroll
        for (int k = 0; k < KSPLIT; ++k)
            o += wn[head * KSPLIT + k] * bf2f(PO[(b0 + k) * 32 + dim]);
        size_t idx = (size_t)n2 * HH + t;
        u16 h = f2bf(o);
        atthi[idx] = h;
        attlo[idx] = f2bf(o - bf2f(h));
        return;
    }

    // ---- GAT node path ----
    int n = blockIdx.x;
    int base = rowstart[n], c = cnt[n];
    float4 adv = ((const float4*)ald)[n];
    float ad[4] = {adv.x, adv.y, adv.z, adv.w};
    float M2[4];
#pragma unroll
    for (int h = 0; h < 4; ++h) {
        float bound = decf(gmax[h]) + decf(gmax[4 + h]);
        float M = bound >= 0.f ? bound : 0.2f * bound;
        M2[h] = M * L2E;
    }
    float dsum[4] = {0.f, 0.f, 0.f, 0.f};
    // paired-edge accumulators: this thread covers dims (2d, 2d+1) for edges with idx%2==eh
    int eh = t >> 6, d = t & 63, hd = d >> 4;
    float acc0 = 0.f, acc1 = 0.f;
    int ht = t >> 5;
    for (int ch = 0; ch < c; ch += GCHUNK) {
        int cn = min(GCHUNK, c - ch);
        __syncthreads();
        for (int i = t; i < cn; i += 128) {
            int s = esrc[base + ch + i];
            slds[i] = s;
            float4 as = ((const float4*)als)[s];
            float lg, e;
            lg = as.x + ad[0]; lg = lg >= 0.f ? lg : 0.2f * lg; e = __builtin_exp2f(lg * L2E - M2[0]); elds[i * 4 + 0] = e; dsum[0] += e;
            lg = as.y + ad[1]; lg = lg >= 0.f ? lg : 0.2f * lg; e = __builtin_exp2f(lg * L2E - M2[1]); elds[i * 4 + 1] = e; dsum[1] += e;
            lg = as.z + ad[2]; lg = lg >= 0.f ? lg : 0.2f * lg; e = __builtin_exp2f(lg * L2E - M2[2]); elds[i * 4 + 2] = e; dsum[2] += e;
            lg = as.w + ad[3]; lg = lg >= 0.f ? lg : 0.2f * lg; e = __builtin_exp2f(lg * L2E - M2[3]); elds[i * 4 + 3] = e; dsum[3] += e;
        }
        __syncthreads();
        for (int i = 0; i < cn; i += 4) {
            int i0 = i + eh, i1 = i + 2 + eh;
            int s0 = slds[i0 < cn ? i0 : cn - 1];
            int s1 = slds[i1 < cn ? i1 : cn - 1];
            u32 x0 = *(const u32*)(xpb + (size_t)s0 * HH + 2 * d);
            u32 x1 = *(const u32*)(xpb + (size_t)s1 * HH + 2 * d);
            float w0 = (i0 < cn) ? elds[i0 * 4 + hd] : 0.f;
            float w1 = (i1 < cn) ? elds[i1 * 4 + hd] : 0.f;
            acc0 += w0 * bf2f((u16)(x0 & 0xFFFF)) + w1 * bf2f((u16)(x1 & 0xFFFF));
            acc1 += w0 * bf2f((u16)(x0 >> 16)) + w1 * bf2f((u16)(x1 >> 16));
        }
    }
    __syncthreads();
#pragma unroll
    for (int h = 0; h < 4; ++h) red[h * 128 + t] = dsum[h];
    // paired-acc combine staging (elds reuse; safe: all elds reads done before this sync's release)
    elds[eh * 128 + 2 * d] = acc0;
    elds[eh * 128 + 2 * d + 1] = acc1;
    __syncthreads();
    for (int s2 = 64; s2 > 0; s2 >>= 1) {
        if (t < s2) {
#pragma unroll
            for (int h = 0; h < 4; ++h)
                red[h * 128 + t] += red[h * 128 + t + s2];
        }
        __syncthreads();
    }
    float accf = elds[t] + elds[128 + t];
    float inv = 1.f / (red[ht * 128] + 1e-16f);
    gatout[(size_t)n * HH + t] = accf * inv;
}

extern "C" void kernel_launch(void* const* d_in, const int* in_sizes, int n_in,
                              void* d_out, int out_size, void* d_ws, size_t ws_size,
                              hipStream_t stream) {
    float* W = (float*)d_ws;
    size_t o = 0;
    auto take = [&](size_t n) { size_t r = o; o += n; return r; };
    size_t pb_in = take(HH);
    size_t pattS = take(LL * HEADS * DH);
    size_t pattD = take(LL * HEADS * DH);
    size_t pb_gat = take(LL * HH);
    size_t pb_qkv = take(LL * 3 * HH);
    size_t pb_o  = take(LL * HH);
    size_t pbn_g = take(LL * 3 * HH);
    size_t pbn_b = take(LL * 3 * HH);
    size_t pb1   = take(LL * 2 * HH);
    size_t pb2   = take(LL * HH);
    size_t pw_out = take(2 * HH);
    size_t pb_out = take(2);
    auto takeb = [&](size_t nu16) { size_t r = o; o += (nu16 + 1) / 2; return r; };
    size_t bw_in  = takeb(HH * INF_);
    size_t bw_gat = takeb(LL * HH * HH);
    size_t bw_qkv = takeb(LL * 3 * HH * HH);
    size_t bw_o   = takeb(LL * HH * HH);
    size_t bw1    = takeb(LL * 2 * HH * HH);
    size_t bw2    = takeb(LL * HH * 2 * HH);
    o = (o + 127) & ~(size_t)127;
    size_t ohbuf = take(NH);
    size_t ogat  = take(NH);
    size_t oals  = take(NN * HEADS);
    size_t oald  = take(NN * HEADS);
    size_t opm   = take(NN * HEADS * KSPLIT);
    size_t opl   = take(NN * HEADS * KSPLIT);
    size_t opo   = takeb((size_t)NN * HEADS * KSPLIT * 32);
    size_t oqkvb = takeb(NN * 384);
    size_t oxpb  = takeb(NH);
    size_t oxhi  = takeb(NN * INF_);
    size_t oxlo  = takeb(NN * INF_);
    size_t ohhi  = takeb(NH);
    size_t ohlo  = takeb(NH);
    size_t oahi  = takeb(NH);
    size_t oalo  = takeb(NH);
    int* ibase    = (int*)(W + o);
    int* iflag    = ibase;
    int* cnt      = ibase + 64;
    int* rowstart = cnt + NN;
    int* cursor   = rowstart + NN;
    int* esrc     = cursor + NN;
    u32* gmax     = (u32*)(esrc + EE);

    float* hbuf = W + ohbuf;
    float* gatb = W + ogat;
    float* als  = W + oals;
    float* ald  = W + oald;
    float* pmb  = W + opm;
    float* plb  = W + opl;
    u16* pob  = (u16*)(W + opo);
    u16* qkvb = (u16*)(W + oqkvb);
    u16* xpb  = (u16*)(W + oxpb);
    u16* xhi = (u16*)(W + oxhi), *xlo = (u16*)(W + oxlo);
    u16* hhi = (u16*)(W + ohhi), *hlo = (u16*)(W + ohlo);
    u16* ahi = (u16*)(W + oahi), *alo = (u16*)(W + oalo);

    const int* src = (const int*)d_in[1];
    const int* dst = (const int*)d_in[1] + EE;
    const u16* dw_in  = (const u16*)d_in[2];
    const u16* dw_gat = (const u16*)d_in[4];
    const u16* dw_qkv = (const u16*)d_in[8];
    const u16* dw_o   = (const u16*)d_in[10];
    const u16* dw1    = (const u16*)d_in[14];
    const u16* dw2    = (const u16*)d_in[16];

    k_detect<<<1, 256, 0, stream>>>((const u16*)d_in[0], iflag, cnt, gmax);

    SegF SF = {};
    int nf = 0;
    auto addf = [&](int idx, size_t off, int n) { SF.src[nf] = d_in[idx]; SF.dst[nf] = (int)off; SF.n[nf] = n; ++nf; };
    addf(3, pb_in, HH);
    addf(5, pattS, LL * HEADS * DH);
    addf(6, pattD, LL * HEADS * DH);
    addf(7, pb_gat, LL * HH);
    addf(9, pb_qkv, LL * 3 * HH);
    addf(11, pb_o, LL * HH);
    addf(12, pbn_g, LL * 3 * HH);
    addf(13, pbn_b, LL * 3 * HH);
    addf(15, pb1, LL * 2 * HH);
    addf(17, pb2, LL * HH);
    addf(18, pw_out, 2 * HH);
    addf(19, pb_out, 2);
    SF.cnt = nf;

    SegB SB = {};
    int nb = 0;
    auto addb = [&](int idx, size_t off, int n, u16* d2) {
        SB.src[nb] = d_in[idx]; SB.dst[nb] = (u16*)(W + off); SB.dst2[nb] = d2; SB.n[nb] = n; ++nb;
    };
    addb(2, bw_in, HH * INF_, nullptr);
    addb(4, bw_gat, LL * HH * HH, nullptr);
    addb(8, bw_qkv, LL * 3 * HH * HH, nullptr);
    addb(10, bw_o, LL * HH * HH, nullptr);
    addb(14, bw1, LL * 2 * HH * HH, nullptr);
    addb(16, bw2, LL * HH * 2 * HH, nullptr);
    SB.src[nb] = d_in[0]; SB.dst[nb] = xhi; SB.dst2[nb] = xlo; SB.n[nb] = NN * INF_; ++nb;
    SB.cnt = nb;

    // merged cvtf + cvtb + hist: 96 + 896 + 1024 blocks
    k_prep<<<2016, 256, 0, stream>>>(SF, W, SB, iflag, dst, cnt);

    // w_in GEMM (j-tile 64) + CSR-scan rider block (y==2)
    k_mgemm<<<dim3(NN / 32, HH / 64 + 1), 128, 0, stream>>>(xhi, xlo, (u16*)(W + bw_in), dw_in, iflag,
                                                            W + pb_in, hbuf, nullptr, hhi, hlo, INF_, HH, 1,
                                                            HH / 64, cnt, rowstart, cursor);

    for (int l = 0; l < LL; ++l) {
        // gq GEMM (8 j-blocks) + scatter rider (layer 0: y in [8,10))
        k_gemm_gq<<<dim3(NN / 32, (l == 0) ? 10 : 8), 128, 0, stream>>>(hhi, hlo,
                                                        (u16*)(W + bw_gat) + (size_t)l * HH * HH,
                                                        dw_gat + (size_t)l * HH * HH,
                                                        (u16*)(W + bw_qkv) + (size_t)l * 3 * HH * HH,
                                                        dw_qkv + (size_t)l * 3 * HH * HH,
                                                        iflag, W + pb_qkv + l * 3 * HH, xpb, qkvb,
                                                        src, dst, cursor, esrc);
        // merged mha_split (32*HEADS*KSPLIT = 1024) + attlog (64)
        k_splitlog<<<32 * HEADS * KSPLIT + (NN * HEADS) / 256, 256, 0, stream>>>(qkvb, pmb, plb, pob, xpb,
                                                                  W + pattS + l * HEADS * DH,
                                                                  W + pattD + l * HEADS * DH,
                                                                  als, ald, gmax + l * 8);
        // merged gat_node (NN) + mha_comb (NN)
        k_gatcomb<<<2 * NN, 128, 0, stream>>>(esrc, rowstart, cnt, als, ald, xpb, gatb, gmax + l * 8,
                                              pmb, plb, pob, ahi, alo);
        // fused w_o + combine + MLP (+ output projection on last layer)
        k_womlp<<<NN / 16, 256, 0, stream>>>(ahi, alo,
                                             (u16*)(W + bw_o) + (size_t)l * HH * HH,
                                             dw_o + (size_t)l * HH * HH,
                                             (u16*)(W + bw1) + (size_t)l * 2 * HH * HH,
                                             dw1 + (size_t)l * 2 * HH * HH,
                                             (u16*)(W + bw2) + (size_t)l * HH * 2 * HH,
                                             dw2 + (size_t)l * HH * 2 * HH, iflag,
                                             W + pb_o + l * HH, W + pb1 + l * 2 * HH, W + pb2 + l * HH,
                                             gatb, W + pb_gat + l * HH,
                                             W + pbn_g + l * 3 * HH, W + pbn_b + l * 3 * HH,
                                             W + pbn_g + l * 3 * HH + 2 * HH,
                                             W + pbn_b + l * 3 * HH + 2 * HH,
                                             hbuf, hhi, hlo,
                                             W + pw_out, W + pb_out,
                                             (l == LL - 1) ? d_out : nullptr);
    }
}

// Round 11
// 269.479 us; speedup vs baseline: 1.0289x; 1.0289x over previous
//
#include <hip/hip_runtime.h>

#define NN 4096
#define EE 262144
#define INF_ 64
#define HH 128
#define HEADS 4
#define DH 32
#define LL 2
#define NH (NN * HH)
#define KSPLIT 16
#define L2E 1.4426950408889634f

typedef unsigned short u16;
typedef unsigned int u32;
using bf16x8 = __attribute__((ext_vector_type(8))) short;
using f32x4 = __attribute__((ext_vector_type(4))) float;

__device__ __forceinline__ float bf2f(u16 v) { return __uint_as_float(((u32)v) << 16); }
__device__ __forceinline__ u16 f2bf(float f) {
    u32 u = __float_as_uint(f);
    u32 r = (u + 0x7fffu + ((u >> 16) & 1u)) >> 16;
    return (u16)r;
}
__device__ __forceinline__ u32 encf(float f) {
    u32 b = __float_as_uint(f);
    return (b & 0x80000000u) ? ~b : (b | 0x80000000u);
}
__device__ __forceinline__ float decf(u32 u) {
    u32 b = (u & 0x80000000u) ? (u & 0x7fffffffu) : ~u;
    return __uint_as_float(b);
}

// ---------------- dtype detect + zero-init (cnt, gmax) ----------------
__global__ __launch_bounds__(256) void k_detect(const u16* __restrict__ x, int* __restrict__ flag,
                                                int* __restrict__ cnt, u32* __restrict__ gmax) {
    int t = threadIdx.x;
    for (int i = t; i < NN; i += 256) cnt[i] = 0;
    if (t < 16) gmax[t] = 0;
    __shared__ int cs[256];
    u16 v = x[2 * t];
    int e = (v >> 7) & 0xFF;
    cs[t] = (e >= 100 && e <= 140) ? 1 : 0;
    __syncthreads();
    for (int s = 128; s > 0; s >>= 1) {
        if (t < s) cs[t] += cs[t + s];
        __syncthreads();
    }
    if (t == 0) *flag = (cs[0] >= 128) ? 1 : 0;
}

// ---------------- merged param conversion + edge histogram ----------------
#define MAXSEG 16
struct SegF { const void* src[MAXSEG]; int dst[MAXSEG]; int n[MAXSEG]; int cnt; };
struct SegB { const void* src[8]; u16* dst[8]; u16* dst2[8]; int n[8]; int cnt; };
// blocks [0,96): cvtf (8 per seg x 12), [96,992): cvtb (128 per seg x 7), [992,2016): hist
__global__ __launch_bounds__(256) void k_prep(SegF SF, float* __restrict__ W, SegB SB,
                                              const int* __restrict__ flag,
                                              const int* __restrict__ dst, int* __restrict__ cnt) {
    int bid = blockIdx.x, t = threadIdx.x;
    if (bid < 96) {
        int seg = bid >> 3, bx = bid & 7;
        if (seg >= SF.cnt) return;
        int n = SF.n[seg];
        float* d = W + SF.dst[seg];
        const void* s = SF.src[seg];
        int f = *flag;
        for (int i = bx * 256 + t; i < n; i += 8 * 256)
            d[i] = f ? bf2f(((const u16*)s)[i]) : ((const float*)s)[i];
    } else if (bid < 992) {
        int b2 = bid - 96;
        int seg = b2 >> 7, bx = b2 & 127;
        if (seg >= SB.cnt) return;
        int f = *flag;
        u16* d = SB.dst[seg];
        u16* d2 = SB.dst2[seg];
        if (f && !d2) return;   // weights already bf16 in d_in
        int n = SB.n[seg];
        const void* s = SB.src[seg];
        for (int i = bx * 256 + t; i < n; i += 128 * 256) {
            if (d2) {
                float v = f ? bf2f(((const u16*)s)[i]) : ((const float*)s)[i];
                u16 h = f2bf(v);
                d[i] = h;
                d2[i] = f2bf(v - bf2f(h));
            } else {
                d[i] = f2bf(((const float*)s)[i]);
            }
        }
    } else {
        int e = (bid - 992) * 256 + t;
        if (e < EE) atomicAdd(&cnt[dst[e]], 1);
    }
}

// ---------------- generic MFMA GEMM, M-tile 32 / J-tile 64 (acc[4]) ----------------
// blockIdx.y >= jtiles: CSR scan rider block (x==0 only; runs after k_prep's hist).
__global__ __launch_bounds__(128) void k_mgemm(const u16* __restrict__ Ahi, const u16* __restrict__ Alo,
                                               const u16* __restrict__ Wc, const u16* __restrict__ Wd,
                                               const int* __restrict__ flag,
                                               const float* __restrict__ bias,
                                               float* __restrict__ outf, u16* __restrict__ outb16,
                                               u16* __restrict__ outhi, u16* __restrict__ outlo,
                                               int K, int J, int relu, int jtiles,
                                               const int* __restrict__ scnt, int* __restrict__ srowstart,
                                               int* __restrict__ scursor) {
    __shared__ int part[128];
    if ((int)blockIdx.y >= jtiles) {
        // ---- 128-thread CSR scan (NN = 128 x 32) ----
        if (blockIdx.x != 0 || scnt == nullptr) return;
        int t = threadIdx.x;
        int loc[32];
        int s = 0;
#pragma unroll
        for (int i = 0; i < 32; ++i) { loc[i] = s; s += scnt[t * 32 + i]; }
        part[t] = s;
        __syncthreads();
        for (int off = 1; off < 128; off <<= 1) {
            int v = part[t];
            int a = (t >= off) ? part[t - off] : 0;
            __syncthreads();
            part[t] = v + a;
            __syncthreads();
        }
        int base = (t == 0) ? 0 : part[t - 1];
#pragma unroll
        for (int i = 0; i < 32; ++i) {
            srowstart[t * 32 + i] = base + loc[i];
            scursor[t * 32 + i] = base + loc[i];
        }
        return;
    }
    const u16* Wb = (*flag) ? Wd : Wc;
    int wave = threadIdx.x >> 6, lane = threadIdx.x & 63;
    int grp = lane >> 4, lcol = lane & 15;
    int m0 = blockIdx.x * 32 + wave * 16;
    int j0 = blockIdx.y * 64;
    f32x4 acc[4];
#pragma unroll
    for (int s = 0; s < 4; ++s) acc[s] = (f32x4){0.f, 0.f, 0.f, 0.f};
    const u16* ah = Ahi + (size_t)(m0 + lcol) * K + grp * 8;
    const u16* al = Alo + (size_t)(m0 + lcol) * K + grp * 8;
    const u16* wb = Wb + (size_t)(j0 + lcol) * K + grp * 8;
    for (int k = 0; k < K; k += 32) {
        bf16x8 va = *(const bf16x8*)(ah + k);
        bf16x8 vl = *(const bf16x8*)(al + k);
#pragma unroll
        for (int s = 0; s < 4; ++s) {
            bf16x8 vw = *(const bf16x8*)(wb + (size_t)s * 16 * K + k);
            acc[s] = __builtin_amdgcn_mfma_f32_16x16x32_bf16(va, vw, acc[s], 0, 0, 0);
            acc[s] = __builtin_amdgcn_mfma_f32_16x16x32_bf16(vl, vw, acc[s], 0, 0, 0);
        }
    }
#pragma unroll
    for (int s = 0; s < 4; ++s) {
        int col = j0 + s * 16 + lcol;
        float bs = bias ? bias[col] : 0.f;
#pragma unroll
        for (int r = 0; r < 4; ++r) {
            float v = acc[s][r] + bs;
            if (relu) v = fmaxf(v, 0.f);
            size_t idx = (size_t)(m0 + grp * 4 + r) * J + col;
            if (outf) outf[idx] = v;
            if (outb16) outb16[idx] = f2bf(v);
            if (outhi) {
                u16 hv = f2bf(v);
                outhi[idx] = hv;
                outlo[idx] = f2bf(v - bf2f(hv));
            }
        }
    }
}

// ---------------- fused GAT-xp + QKV GEMM, J-tile 64 (+ scatter rider blocks y>=8) ----------------
__global__ __launch_bounds__(128) void k_gemm_gq(const u16* __restrict__ Ahi, const u16* __restrict__ Alo,
                                                 const u16* __restrict__ wgatc, const u16* __restrict__ wgatd,
                                                 const u16* __restrict__ wqkvc, const u16* __restrict__ wqkvd,
                                                 const int* __restrict__ flag,
                                                 const float* __restrict__ bqkv,
                                                 u16* __restrict__ xpb, u16* __restrict__ qkvb,
                                                 const int* __restrict__ esrc_src, const int* __restrict__ esrc_dst,
                                                 int* __restrict__ cursor, int* __restrict__ esrc) {
    if (blockIdx.y >= 8) {
        // ---- CSR scatter rider (layer 0 only; 256 blocks x 128 thr) ----
        int b = (blockIdx.y - 8) * 128 + blockIdx.x;
        for (int e = b * 128 + threadIdx.x; e < EE; e += 32768) {
            int d = esrc_dst[e];
            int p = atomicAdd(&cursor[d], 1);
            esrc[p] = esrc_src[e];
        }
        return;
    }
    int wave = threadIdx.x >> 6, lane = threadIdx.x & 63;
    int grp = lane >> 4, lcol = lane & 15;
    int m0 = blockIdx.x * 32 + wave * 16;
    int jb = blockIdx.y;
    int j0 = jb * 64;
    int f = *flag;
    const u16* wgat = f ? wgatd : wgatc;
    const u16* wqkv = f ? wqkvd : wqkvc;
    const u16* Wb = (jb < 2) ? (wgat + (size_t)j0 * HH) : (wqkv + (size_t)(j0 - 128) * HH);
    f32x4 acc[4];
#pragma unroll
    for (int s = 0; s < 4; ++s) acc[s] = (f32x4){0.f, 0.f, 0.f, 0.f};
    const u16* ah = Ahi + (size_t)(m0 + lcol) * HH + grp * 8;
    const u16* al = Alo + (size_t)(m0 + lcol) * HH + grp * 8;
    const u16* wb = Wb + (size_t)lcol * HH + grp * 8;
    for (int k = 0; k < HH; k += 32) {
        bf16x8 va = *(const bf16x8*)(ah + k);
        bf16x8 vl = *(const bf16x8*)(al + k);
#pragma unroll
        for (int s = 0; s < 4; ++s) {
            bf16x8 vw = *(const bf16x8*)(wb + (size_t)s * 16 * HH + k);
            acc[s] = __builtin_amdgcn_mfma_f32_16x16x32_bf16(va, vw, acc[s], 0, 0, 0);
            acc[s] = __builtin_amdgcn_mfma_f32_16x16x32_bf16(vl, vw, acc[s], 0, 0, 0);
        }
    }
    if (jb < 2) {
#pragma unroll
        for (int s = 0; s < 4; ++s) {
            int col = j0 + s * 16 + lcol;
#pragma unroll
            for (int r = 0; r < 4; ++r)
                xpb[(size_t)(m0 + grp * 4 + r) * HH + col] = f2bf(acc[s][r]);
        }
    } else {
#pragma unroll
        for (int s = 0; s < 4; ++s) {
            int colq = j0 - 128 + s * 16 + lcol;
            float bs = bqkv[colq];
#pragma unroll
            for (int r = 0; r < 4; ++r)
                qkvb[(size_t)(m0 + grp * 4 + r) * 384 + colq] = f2bf(acc[s][r] + bs);
        }
    }
}

// ---------------- fused w_o + combine + MLP (+ optional output projection) ----------------
__global__ __launch_bounds__(256) void k_womlp(const u16* __restrict__ Ahi, const u16* __restrict__ Alo,
                                               const u16* __restrict__ Woc, const u16* __restrict__ Wod,
                                               const u16* __restrict__ W1c, const u16* __restrict__ W1d,
                                               const u16* __restrict__ W2c, const u16* __restrict__ W2d,
                                               const int* __restrict__ flag,
                                               const float* __restrict__ bo, const float* __restrict__ b1,
                                               const float* __restrict__ b2,
                                               const float* __restrict__ gatb, const float* __restrict__ bgat,
                                               const float* __restrict__ gam, const float* __restrict__ bet,
                                               const float* __restrict__ gam2, const float* __restrict__ bet2,
                                               float* __restrict__ hbuf, u16* __restrict__ hhi,
                                               u16* __restrict__ hlo,
                                               const float* __restrict__ wout, const float* __restrict__ bout,
                                               void* __restrict__ yout) {
    __shared__ float Of[16][132];                 // 8448 B (528 B row stride)
    __shared__ u16 A2hi[16][136], A2lo[16][136];  // 4352 B each (272 B stride, 16B-aligned)
    __shared__ u16 Hhi[16][264], Hlo[16][264];    // 8448 B each
    int f = *flag;
    const u16* Wo = f ? Wod : Woc;
    const u16* W1 = f ? W1d : W1c;
    const u16* W2 = f ? W2d : W2c;
    int wave = threadIdx.x >> 6, lane = threadIdx.x & 63;
    int grp = lane >> 4, lcol = lane & 15;
    int m0 = blockIdx.x * 16;
    float rs = rsqrtf(1.00001f);

    // ---- phase A: wo GEMM (K=128) + combine epilogue -> LDS ----
    {
        int j0 = wave * 32;
        f32x4 acc[2];
#pragma unroll
        for (int s = 0; s < 2; ++s) acc[s] = (f32x4){0.f, 0.f, 0.f, 0.f};
        const u16* ah = Ahi + (size_t)(m0 + lcol) * HH + grp * 8;
        const u16* al = Alo + (size_t)(m0 + lcol) * HH + grp * 8;
        const u16* wb = Wo + (size_t)(j0 + lcol) * HH + grp * 8;
#pragma unroll
        for (int k = 0; k < HH; k += 32) {
            bf16x8 va = *(const bf16x8*)(ah + k);
            bf16x8 vl = *(const bf16x8*)(al + k);
#pragma unroll
            for (int s = 0; s < 2; ++s) {
                bf16x8 vw = *(const bf16x8*)(wb + (size_t)s * 16 * HH + k);
                acc[s] = __builtin_amdgcn_mfma_f32_16x16x32_bf16(va, vw, acc[s], 0, 0, 0);
                acc[s] = __builtin_amdgcn_mfma_f32_16x16x32_bf16(vl, vw, acc[s], 0, 0, 0);
            }
        }
#pragma unroll
        for (int s = 0; s < 2; ++s) {
            int col = j0 + s * 16 + lcol;
            float bs = bo[col];
            float g0 = gam[col] * rs, b0 = bet[col];
            float g1 = gam[HH + col] * rs, bb1 = bet[HH + col];
            float bg = bgat[col];
#pragma unroll
            for (int r = 0; r < 4; ++r) {
                int row = grp * 4 + r;
                size_t idx = (size_t)(m0 + row) * HH + col;
                float proj = acc[s][r] + bs;
                float hv = hbuf[idx];
                float hl = g0 * (gatb[idx] + bg + hv) + b0;
                float ha = g1 * (proj + hv) + bb1;
                float v = hl + ha;
                Of[row][col] = v;
                u16 hb = f2bf(v);
                A2hi[row][col] = hb;
                A2lo[row][col] = f2bf(v - bf2f(hb));
            }
        }
    }
    __syncthreads();
    // ---- phase B: w1 GEMM (K=128 from LDS) -> hidden hi/lo in LDS ----
    {
        int j0 = wave * 64;
        f32x4 acc[4];
#pragma unroll
        for (int s = 0; s < 4; ++s) acc[s] = (f32x4){0.f, 0.f, 0.f, 0.f};
        const u16* wb = W1 + (size_t)(j0 + lcol) * HH + grp * 8;
#pragma unroll
        for (int k = 0; k < HH; k += 32) {
            bf16x8 va = *(const bf16x8*)(&A2hi[lcol][k + grp * 8]);
            bf16x8 vl = *(const bf16x8*)(&A2lo[lcol][k + grp * 8]);
#pragma unroll
            for (int s = 0; s < 4; ++s) {
                bf16x8 vw = *(const bf16x8*)(wb + (size_t)s * 16 * HH + k);
                acc[s] = __builtin_amdgcn_mfma_f32_16x16x32_bf16(va, vw, acc[s], 0, 0, 0);
                acc[s] = __builtin_amdgcn_mfma_f32_16x16x32_bf16(vl, vw, acc[s], 0, 0, 0);
            }
        }
#pragma unroll
        for (int s = 0; s < 4; ++s) {
            int col = j0 + s * 16 + lcol;
            float bs = b1[col];
#pragma unroll
            for (int r = 0; r < 4; ++r) {
                float v = fmaxf(acc[s][r] + bs, 0.f);
                int row = grp * 4 + r;
                u16 hv = f2bf(v);
                Hhi[row][col] = hv;
                Hlo[row][col] = f2bf(v - bf2f(hv));
            }
        }
    }
    __syncthreads();
    // ---- phase C: w2 GEMM (K=256 from LDS) + final epilogue ----
    {
        int j0 = wave * 32;
        f32x4 acc[2];
#pragma unroll
        for (int s = 0; s < 2; ++s) acc[s] = (f32x4){0.f, 0.f, 0.f, 0.f};
        const u16* wb = W2 + (size_t)(j0 + lcol) * 256 + grp * 8;
#pragma unroll
        for (int k = 0; k < 256; k += 32) {
            bf16x8 va = *(const bf16x8*)(&Hhi[lcol][k + grp * 8]);
            bf16x8 vl = *(const bf16x8*)(&Hlo[lcol][k + grp * 8]);
#pragma unroll
            for (int s = 0; s < 2; ++s) {
                bf16x8 vw = *(const bf16x8*)(wb + (size_t)s * 16 * 256 + k);
                acc[s] = __builtin_amdgcn_mfma_f32_16x16x32_bf16(va, vw, acc[s], 0, 0, 0);
                acc[s] = __builtin_amdgcn_mfma_f32_16x16x32_bf16(vl, vw, acc[s], 0, 0, 0);
            }
        }
#pragma unroll
        for (int s = 0; s < 2; ++s) {
            int col = j0 + s * 16 + lcol;
            float bs = b2[col];
            float g2 = gam2[col] * rs, bb2 = bet2[col];
#pragma unroll
            for (int r = 0; r < 4; ++r) {
                int row = grp * 4 + r;
                size_t idx = (size_t)(m0 + row) * HH + col;
                float mlpo = acc[s][r] + bs;
                float o2 = g2 * (Of[row][col] + mlpo) + bb2;
                float v = fmaxf(o2 + hbuf[idx], 0.f);
                hbuf[idx] = v;
                Of[row][col] = v;  // stash final h for output projection
                u16 hb = f2bf(v);
                hhi[idx] = hb;
                hlo[idx] = f2bf(v - bf2f(hb));
            }
        }
    }
    // ---- optional output projection (last layer): y[row] = h . w_out^T + b_out ----
    if (yout) {
        __syncthreads();
        int row = threadIdx.x >> 4, sub = threadIdx.x & 15;
        float a0 = 0.f, a1 = 0.f;
#pragma unroll
        for (int k8 = 0; k8 < 8; ++k8) {
            int k = sub * 8 + k8;
            float hv = Of[row][k];
            a0 += hv * wout[k];
            a1 += hv * wout[HH + k];
        }
#pragma unroll
        for (int off = 1; off < 16; off <<= 1) {
            a0 += __shfl_xor(a0, off);
            a1 += __shfl_xor(a1, off);
        }
        if (sub == 0) {
            int n = m0 + row;
            float o0 = a0 + bout[0], o1 = a1 + bout[1];
            if (f) {
                u16* y = (u16*)yout;
                y[n * 2 + 0] = f2bf(o0);
                y[n * 2 + 1] = f2bf(o1);
            } else {
                float* y = (float*)yout;
                y[n * 2 + 0] = o0;
                y[n * 2 + 1] = o1;
            }
        }
    }
}

// ---------------- merged MHA flash split + attlog (blocks >= 2048) ----------------
// split part: 32-key P chunks (LDS 19 KB -> 8 blocks/CU), kappa32 V layout.
// T13 defer-max: skip O/l rescale unless wave-any max growth > 6 (P bounded by 2^6, safe).
__global__ __launch_bounds__(256) void k_splitlog(const u16* __restrict__ qkvb,
                                                  float* __restrict__ PM, float* __restrict__ PL,
                                                  u16* __restrict__ PO,
                                                  const u16* __restrict__ xpb,
                                                  const float* __restrict__ asrc,
                                                  const float* __restrict__ adst,
                                                  float* __restrict__ als, float* __restrict__ ald,
                                                  u32* __restrict__ gmax) {
    __shared__ __align__(16) u16 Klds[64][40];     // 5120 B
    __shared__ __align__(16) u32 Vlds[32][40];     // 5120 B
    __shared__ __align__(16) u16 Plds[4][32][36];  // 9216 B

    if (blockIdx.x >= 32 * HEADS * KSPLIT) {
        // ---- attlog path (64 blocks) ----
        float* red = (float*)&Klds[0][0];  // 1 KB alias
        int t = (blockIdx.x - 32 * HEADS * KSPLIT) * 256 + threadIdx.x;
        int n = t >> 2, hh = t & 3;
        const u16* xr = xpb + (size_t)n * HH + hh * DH;
        float s1 = 0.f, s2 = 0.f;
#pragma unroll
        for (int d = 0; d < DH; ++d) {
            float v = bf2f(xr[d]);
            s1 += v * asrc[hh * DH + d];
            s2 += v * adst[hh * DH + d];
        }
        als[t] = s1;
        ald[t] = s2;
        int lt = threadIdx.x;
        red[lt] = s1;
        __syncthreads();
        for (int off = 128; off >= 4; off >>= 1) {
            if (lt < off) red[lt] = fmaxf(red[lt], red[lt + off]);
            __syncthreads();
        }
        if (lt < 4) atomicMax(&gmax[lt], encf(red[lt]));
        __syncthreads();
        red[lt] = s2;
        __syncthreads();
        for (int off = 128; off >= 4; off >>= 1) {
            if (lt < off) red[lt] = fmaxf(red[lt], red[lt + off]);
            __syncthreads();
        }
        if (lt < 4) atomicMax(&gmax[4 + lt], encf(red[lt]));
        return;
    }

    // ---- flash split path ----
    const float C1 = 0.17677669529663687f * L2E;
    int head = blockIdx.x & 3;
    int qt = (blockIdx.x >> 2) & 31;
    int ks = blockIdx.x >> 7;
    int tid = threadIdx.x;
    int wave = tid >> 6, lane = tid & 63;
    int grp = lane >> 4, lcol = lane & 15;

    int qrow0 = qt * 128 + wave * 32;
    bf16x8 aQ0 = *(const bf16x8*)(qkvb + (size_t)(qrow0 + lcol) * 384 + head * 32 + grp * 8);
    bf16x8 aQ1 = *(const bf16x8*)(qkvb + (size_t)(qrow0 + 16 + lcol) * 384 + head * 32 + grp * 8);

    short onev = (lcol == 0) ? (short)0x3F80 : (short)0;
    bf16x8 bOne = {onev, onev, onev, onev, onev, onev, onev, onev};

    f32x4 oc00 = {0.f, 0.f, 0.f, 0.f}, oc01 = {0.f, 0.f, 0.f, 0.f};
    f32x4 oc10 = {0.f, 0.f, 0.f, 0.f}, oc11 = {0.f, 0.f, 0.f, 0.f};
    f32x4 ol0 = {0.f, 0.f, 0.f, 0.f}, ol1 = {0.f, 0.f, 0.f, 0.f};
    float msh = -INFINITY;

    int isK = (tid < 128);
    int st = tid & 127;
    int skey = st >> 1, shalf = (st & 1) * 16;
    int vj = st & 15, vc = (st >> 4) & 1, dgrp = st >> 5;
    const u16* kptr = qkvb + 128 + head * 32 + shalf;
    const u16* vptr = qkvb + 256 + head * 32 + dgrp * 8;
    int vk0 = vc * 32 + vj;
    int vk1 = vc * 32 + 16 + vj;

    int kt0 = ks * (NN / KSPLIT);
    bf16x8 r0, r1;
    if (isK) {
        r0 = *(const bf16x8*)(kptr + (size_t)(kt0 + skey) * 384);
        r1 = *(const bf16x8*)(kptr + (size_t)(kt0 + skey) * 384 + 8);
    } else {
        r0 = *(const bf16x8*)(vptr + (size_t)(kt0 + vk0) * 384);
        r1 = *(const bf16x8*)(vptr + (size_t)(kt0 + vk1) * 384);
    }

    const int NT = (NN / KSPLIT) / 64;
    for (int t = 0; t < NT; ++t) {
        if (isK) {
            *(bf16x8*)(&Klds[skey][shalf]) = r0;
            *(bf16x8*)(&Klds[skey][shalf + 8]) = r1;
        } else {
#pragma unroll
            for (int j = 0; j < 8; ++j)
                Vlds[dgrp * 8 + j][vc * 20 + vj] = (u32)(u16)r0[j] | ((u32)(u16)r1[j] << 16);
        }
        __syncthreads();
        if (t + 1 < NT) {
            int kn = kt0 + (t + 1) * 64;
            if (isK) {
                r0 = *(const bf16x8*)(kptr + (size_t)(kn + skey) * 384);
                r1 = *(const bf16x8*)(kptr + (size_t)(kn + skey) * 384 + 8);
            } else {
                r0 = *(const bf16x8*)(vptr + (size_t)(kn + vk0) * 384);
                r1 = *(const bf16x8*)(vptr + (size_t)(kn + vk1) * 384);
            }
        }
        f32x4 sc0[4], sc1[4];
        f32x4 zero = {0.f, 0.f, 0.f, 0.f};
        __builtin_amdgcn_s_setprio(1);
#pragma unroll
        for (int s = 0; s < 4; ++s) {
            bf16x8 bK = *(const bf16x8*)(&Klds[s * 16 + lcol][grp * 8]);
            sc0[s] = __builtin_amdgcn_mfma_f32_16x16x32_bf16(aQ0, bK, zero, 0, 0, 0);
            sc1[s] = __builtin_amdgcn_mfma_f32_16x16x32_bf16(aQ1, bK, zero, 0, 0, 0);
        }
        __builtin_amdgcn_s_setprio(0);
        float mymax = sc0[0][0];
#pragma unroll
        for (int s = 0; s < 4; ++s)
#pragma unroll
            for (int r = 0; r < 4; ++r) {
                mymax = fmaxf(mymax, sc0[s][r]);
                mymax = fmaxf(mymax, sc1[s][r]);
            }
        mymax = fmaxf(mymax, __shfl_xor(mymax, 1));
        mymax = fmaxf(mymax, __shfl_xor(mymax, 2));
        mymax = fmaxf(mymax, __shfl_xor(mymax, 4));
        mymax = fmaxf(mymax, __shfl_xor(mymax, 8));
        float pm = mymax * C1;
        // T13 defer-max: only rescale when some lane-group's max grew past msh+6.
        if (__any(pm > msh + 6.0f)) {
            float mnew = fmaxf(msh, pm);
            float cc = __builtin_exp2f(msh - mnew);
            msh = mnew;
            oc00 *= cc; oc01 *= cc; ol0 *= cc;
            oc10 *= cc; oc11 *= cc; ol1 *= cc;
        }
#pragma unroll
        for (int c2 = 0; c2 < 2; ++c2) {
#pragma unroll
            for (int r = 0; r < 4; ++r) {
                float p0 = __builtin_exp2f(__builtin_fmaf(sc0[2 * c2][r], C1, -msh));
                float p1 = __builtin_exp2f(__builtin_fmaf(sc0[2 * c2 + 1][r], C1, -msh));
                *(u32*)(&Plds[wave][grp * 4 + r][2 * lcol]) =
                    __builtin_amdgcn_perm(__float_as_uint(p1), __float_as_uint(p0), 0x07060302u);
                float q0 = __builtin_exp2f(__builtin_fmaf(sc1[2 * c2][r], C1, -msh));
                float q1 = __builtin_exp2f(__builtin_fmaf(sc1[2 * c2 + 1][r], C1, -msh));
                *(u32*)(&Plds[wave][16 + grp * 4 + r][2 * lcol]) =
                    __builtin_amdgcn_perm(__float_as_uint(q1), __float_as_uint(q0), 0x07060302u);
            }
            bf16x8 aP0 = *(const bf16x8*)(&Plds[wave][lcol][grp * 8]);
            bf16x8 aP1 = *(const bf16x8*)(&Plds[wave][16 + lcol][grp * 8]);
            bf16x8 bV0 = *(const bf16x8*)(&Vlds[lcol][c2 * 20 + grp * 4]);
            bf16x8 bV1 = *(const bf16x8*)(&Vlds[16 + lcol][c2 * 20 + grp * 4]);
            __builtin_amdgcn_s_setprio(1);
            oc00 = __builtin_amdgcn_mfma_f32_16x16x32_bf16(aP0, bV0, oc00, 0, 0, 0);
            oc01 = __builtin_amdgcn_mfma_f32_16x16x32_bf16(aP0, bV1, oc01, 0, 0, 0);
            ol0 = __builtin_amdgcn_mfma_f32_16x16x32_bf16(aP0, bOne, ol0, 0, 0, 0);
            oc10 = __builtin_amdgcn_mfma_f32_16x16x32_bf16(aP1, bV0, oc10, 0, 0, 0);
            oc11 = __builtin_amdgcn_mfma_f32_16x16x32_bf16(aP1, bV1, oc11, 0, 0, 0);
            ol1 = __builtin_amdgcn_mfma_f32_16x16x32_bf16(aP1, bOne, ol1, 0, 0, 0);
            __builtin_amdgcn_s_setprio(0);
        }
        __syncthreads();
    }
#pragma unroll
    for (int r = 0; r < 4; ++r) {
        int row0 = qrow0 + grp * 4 + r;
        size_t b0 = ((size_t)row0 * HEADS + head) * KSPLIT + ks;
        PO[b0 * 32 + lcol] = f2bf(oc00[r]);
        PO[b0 * 32 + 16 + lcol] = f2bf(oc01[r]);
        int row1 = row0 + 16;
        size_t b1 = ((size_t)row1 * HEADS + head) * KSPLIT + ks;
        PO[b1 * 32 + lcol] = f2bf(oc10[r]);
        PO[b1 * 32 + 16 + lcol] = f2bf(oc11[r]);
        if (lcol == 0) {
            PM[b0] = msh;
            PL[b0] = ol0[r];
            PM[b1] = msh;
            PL[b1] = ol1[r];
        }
    }
}

// ---------------- merged GAT node pass + MHA combine (blocks >= NN) ----------------
// GAT PV gather: u32 loads (2 dims/lane), 128 threads = 2 edges/step (halved load count).
#define GCHUNK 256
__global__ __launch_bounds__(128) void k_gatcomb(const int* __restrict__ esrc, const int* __restrict__ rowstart,
                                                 const int* __restrict__ cnt, const float* __restrict__ als,
                                                 const float* __restrict__ ald, const u16* __restrict__ xpb,
                                                 float* __restrict__ gatout, const u32* __restrict__ gmax,
                                                 const float* __restrict__ PM, const float* __restrict__ PL,
                                                 const u16* __restrict__ PO, u16* __restrict__ atthi,
                                                 u16* __restrict__ attlo) {
    __shared__ float red[512];
    __shared__ float elds[GCHUNK * 4];
    __shared__ int slds[GCHUNK];
    int t = threadIdx.x;

    if (blockIdx.x >= NN) {
        // ---- MHA combine path: one row per block ----
        int n2 = blockIdx.x - NN;
        float* wn = red;  // 64 floats alias
        if (t < 4 * KSPLIT) {
            int head = t >> 4, ks = t & 15;
            size_t b = ((size_t)n2 * HEADS + head) * KSPLIT + ks;
            float pm = PM[b];
            float m = pm;
#pragma unroll
            for (int off = 1; off < KSPLIT; off <<= 1) m = fmaxf(m, __shfl_xor(m, off));
            float w = __builtin_exp2f(pm - m);
            float lw = PL[b] * w;
#pragma unroll
            for (int off = 1; off < KSPLIT; off <<= 1) lw += __shfl_xor(lw, off);
            wn[t] = w / lw;
        }
        __syncthreads();
        int head = t >> 5, dim = t & 31;
        size_t b0 = ((size_t)n2 * HEADS + head) * KSPLIT;
        float o = 0.f;
#pragma unroll
        for (int k = 0; k < KSPLIT; ++k)
            o += wn[head * KSPLIT + k] * bf2f(PO[(b0 + k) * 32 + dim]);
        size_t idx = (size_t)n2 * HH + t;
        u16 h = f2bf(o);
        atthi[idx] = h;
        attlo[idx] = f2bf(o - bf2f(h));
        return;
    }

    // ---- GAT node path ----
    int n = blockIdx.x;
    int base = rowstart[n], c = cnt[n];
    float4 adv = ((const float4*)ald)[n];
    float ad[4] = {adv.x, adv.y, adv.z, adv.w};
    float M2[4];
#pragma unroll
    for (int h = 0; h < 4; ++h) {
        float bound = decf(gmax[h]) + decf(gmax[4 + h]);
        float M = bound >= 0.f ? bound : 0.2f * bound;
        M2[h] = M * L2E;
    }
    float dsum[4] = {0.f, 0.f, 0.f, 0.f};
    // paired-edge accumulators: this thread covers dims (2d, 2d+1) for edges with idx%2==eh
    int eh = t >> 6, d = t & 63, hd = d >> 4;
    float acc0 = 0.f, acc1 = 0.f;
    int ht = t >> 5;
    for (int ch = 0; ch < c; ch += GCHUNK) {
        int cn = min(GCHUNK, c - ch);
        __syncthreads();
        for (int i = t; i < cn; i += 128) {
            int s = esrc[base + ch + i];
            slds[i] = s;
            float4 as = ((const float4*)als)[s];
            float lg, e;
            lg = as.x + ad[0]; lg = lg >= 0.f ? lg : 0.2f * lg; e = __builtin_exp2f(lg * L2E - M2[0]); elds[i * 4 + 0] = e; dsum[0] += e;
            lg = as.y + ad[1]; lg = lg >= 0.f ? lg : 0.2f * lg; e = __builtin_exp2f(lg * L2E - M2[1]); elds[i * 4 + 1] = e; dsum[1] += e;
            lg = as.z + ad[2]; lg = lg >= 0.f ? lg : 0.2f * lg; e = __builtin_exp2f(lg * L2E - M2[2]); elds[i * 4 + 2] = e; dsum[2] += e;
            lg = as.w + ad[3]; lg = lg >= 0.f ? lg : 0.2f * lg; e = __builtin_exp2f(lg * L2E - M2[3]); elds[i * 4 + 3] = e; dsum[3] += e;
        }
        __syncthreads();
        for (int i = 0; i < cn; i += 4) {
            int i0 = i + eh, i1 = i + 2 + eh;
            int s0 = slds[i0 < cn ? i0 : cn - 1];
            int s1 = slds[i1 < cn ? i1 : cn - 1];
            u32 x0 = *(const u32*)(xpb + (size_t)s0 * HH + 2 * d);
            u32 x1 = *(const u32*)(xpb + (size_t)s1 * HH + 2 * d);
            float w0 = (i0 < cn) ? elds[i0 * 4 + hd] : 0.f;
            float w1 = (i1 < cn) ? elds[i1 * 4 + hd] : 0.f;
            acc0 += w0 * bf2f((u16)(x0 & 0xFFFF)) + w1 * bf2f((u16)(x1 & 0xFFFF));
            acc1 += w0 * bf2f((u16)(x0 >> 16)) + w1 * bf2f((u16)(x1 >> 16));
        }
    }
    __syncthreads();
#pragma unroll
    for (int h = 0; h < 4; ++h) red[h * 128 + t] = dsum[h];
    // paired-acc combine staging (elds reuse; safe: all elds reads done before this sync's release)
    elds[eh * 128 + 2 * d] = acc0;
    elds[eh * 128 + 2 * d + 1] = acc1;
    __syncthreads();
    for (int s2 = 64; s2 > 0; s2 >>= 1) {
        if (t < s2) {
#pragma unroll
            for (int h = 0; h < 4; ++h)
                red[h * 128 + t] += red[h * 128 + t + s2];
        }
        __syncthreads();
    }
    float accf = elds[t] + elds[128 + t];
    float inv = 1.f / (red[ht * 128] + 1e-16f);
    gatout[(size_t)n * HH + t] = accf * inv;
}

extern "C" void kernel_launch(void* const* d_in, const int* in_sizes, int n_in,
                              void* d_out, int out_size, void* d_ws, size_t ws_size,
                              hipStream_t stream) {
    float* W = (float*)d_ws;
    size_t o = 0;
    auto take = [&](size_t n) { size_t r = o; o += n; return r; };
    size_t pb_in = take(HH);
    size_t pattS = take(LL * HEADS * DH);
    size_t pattD = take(LL * HEADS * DH);
    size_t pb_gat = take(LL * HH);
    size_t pb_qkv = take(LL * 3 * HH);
    size_t pb_o  = take(LL * HH);
    size_t pbn_g = take(LL * 3 * HH);
    size_t pbn_b = take(LL * 3 * HH);
    size_t pb1   = take(LL * 2 * HH);
    size_t pb2   = take(LL * HH);
    size_t pw_out = take(2 * HH);
    size_t pb_out = take(2);
    auto takeb = [&](size_t nu16) { size_t r = o; o += (nu16 + 1) / 2; return r; };
    size_t bw_in  = takeb(HH * INF_);
    size_t bw_gat = takeb(LL * HH * HH);
    size_t bw_qkv = takeb(LL * 3 * HH * HH);
    size_t bw_o   = takeb(LL * HH * HH);
    size_t bw1    = takeb(LL * 2 * HH * HH);
    size_t bw2    = takeb(LL * HH * 2 * HH);
    o = (o + 127) & ~(size_t)127;
    size_t ohbuf = take(NH);
    size_t ogat  = take(NH);
    size_t oals  = take(NN * HEADS);
    size_t oald  = take(NN * HEADS);
    size_t opm   = take(NN * HEADS * KSPLIT);
    size_t opl   = take(NN * HEADS * KSPLIT);
    size_t opo   = takeb((size_t)NN * HEADS * KSPLIT * 32);
    size_t oqkvb = takeb(NN * 384);
    size_t oxpb  = takeb(NH);
    size_t oxhi  = takeb(NN * INF_);
    size_t oxlo  = takeb(NN * INF_);
    size_t ohhi  = takeb(NH);
    size_t ohlo  = takeb(NH);
    size_t oahi  = takeb(NH);
    size_t oalo  = takeb(NH);
    int* ibase    = (int*)(W + o);
    int* iflag    = ibase;
    int* cnt      = ibase + 64;
    int* rowstart = cnt + NN;
    int* cursor   = rowstart + NN;
    int* esrc     = cursor + NN;
    u32* gmax     = (u32*)(esrc + EE);

    float* hbuf = W + ohbuf;
    float* gatb = W + ogat;
    float* als  = W + oals;
    float* ald  = W + oald;
    float* pmb  = W + opm;
    float* plb  = W + opl;
    u16* pob  = (u16*)(W + opo);
    u16* qkvb = (u16*)(W + oqkvb);
    u16* xpb  = (u16*)(W + oxpb);
    u16* xhi = (u16*)(W + oxhi), *xlo = (u16*)(W + oxlo);
    u16* hhi = (u16*)(W + ohhi), *hlo = (u16*)(W + ohlo);
    u16* ahi = (u16*)(W + oahi), *alo = (u16*)(W + oalo);

    const int* src = (const int*)d_in[1];
    const int* dst = (const int*)d_in[1] + EE;
    const u16* dw_in  = (const u16*)d_in[2];
    const u16* dw_gat = (const u16*)d_in[4];
    const u16* dw_qkv = (const u16*)d_in[8];
    const u16* dw_o   = (const u16*)d_in[10];
    const u16* dw1    = (const u16*)d_in[14];
    const u16* dw2    = (const u16*)d_in[16];

    k_detect<<<1, 256, 0, stream>>>((const u16*)d_in[0], iflag, cnt, gmax);

    SegF SF = {};
    int nf = 0;
    auto addf = [&](int idx, size_t off, int n) { SF.src[nf] = d_in[idx]; SF.dst[nf] = (int)off; SF.n[nf] = n; ++nf; };
    addf(3, pb_in, HH);
    addf(5, pattS, LL * HEADS * DH);
    addf(6, pattD, LL * HEADS * DH);
    addf(7, pb_gat, LL * HH);
    addf(9, pb_qkv, LL * 3 * HH);
    addf(11, pb_o, LL * HH);
    addf(12, pbn_g, LL * 3 * HH);
    addf(13, pbn_b, LL * 3 * HH);
    addf(15, pb1, LL * 2 * HH);
    addf(17, pb2, LL * HH);
    addf(18, pw_out, 2 * HH);
    addf(19, pb_out, 2);
    SF.cnt = nf;

    SegB SB = {};
    int nb = 0;
    auto addb = [&](int idx, size_t off, int n, u16* d2) {
        SB.src[nb] = d_in[idx]; SB.dst[nb] = (u16*)(W + off); SB.dst2[nb] = d2; SB.n[nb] = n; ++nb;
    };
    addb(2, bw_in, HH * INF_, nullptr);
    addb(4, bw_gat, LL * HH * HH, nullptr);
    addb(8, bw_qkv, LL * 3 * HH * HH, nullptr);
    addb(10, bw_o, LL * HH * HH, nullptr);
    addb(14, bw1, LL * 2 * HH * HH, nullptr);
    addb(16, bw2, LL * HH * 2 * HH, nullptr);
    SB.src[nb] = d_in[0]; SB.dst[nb] = xhi; SB.dst2[nb] = xlo; SB.n[nb] = NN * INF_; ++nb;
    SB.cnt = nb;

    // merged cvtf + cvtb + hist: 96 + 896 + 1024 blocks
    k_prep<<<2016, 256, 0, stream>>>(SF, W, SB, iflag, dst, cnt);

    // w_in GEMM (j-tile 64) + CSR-scan rider block (y==2)
    k_mgemm<<<dim3(NN / 32, HH / 64 + 1), 128, 0, stream>>>(xhi, xlo, (u16*)(W + bw_in), dw_in, iflag,
                                                            W + pb_in, hbuf, nullptr, hhi, hlo, INF_, HH, 1,
                                                            HH / 64, cnt, rowstart, cursor);

    for (int l = 0; l < LL; ++l) {
        // gq GEMM (8 j-blocks) + scatter rider (layer 0: y in [8,10))
        k_gemm_gq<<<dim3(NN / 32, (l == 0) ? 10 : 8), 128, 0, stream>>>(hhi, hlo,
                                                        (u16*)(W + bw_gat) + (size_t)l * HH * HH,
                                                        dw_gat + (size_t)l * HH * HH,
                                                        (u16*)(W + bw_qkv) + (size_t)l * 3 * HH * HH,
                                                        dw_qkv + (size_t)l * 3 * HH * HH,
                                                        iflag, W + pb_qkv + l * 3 * HH, xpb, qkvb,
                                                        src, dst, cursor, esrc);
        // merged mha_split (32*HEADS*KSPLIT = 2048) + attlog (64)
        k_splitlog<<<32 * HEADS * KSPLIT + (NN * HEADS) / 256, 256, 0, stream>>>(qkvb, pmb, plb, pob, xpb,
                                                                  W + pattS + l * HEADS * DH,
                                                                  W + pattD + l * HEADS * DH,
                                                                  als, ald, gmax + l * 8);
        // merged gat_node (NN) + mha_comb (NN)
        k_gatcomb<<<2 * NN, 128, 0, stream>>>(esrc, rowstart, cnt, als, ald, xpb, gatb, gmax + l * 8,
                                              pmb, plb, pob, ahi, alo);
        // fused w_o + combine + MLP (+ output projection on last layer)
        k_womlp<<<NN / 16, 256, 0, stream>>>(ahi, alo,
                                             (u16*)(W + bw_o) + (size_t)l * HH * HH,
                                             dw_o + (size_t)l * HH * HH,
                                             (u16*)(W + bw1) + (size_t)l * 2 * HH * HH,
                                             dw1 + (size_t)l * 2 * HH * HH,
                                             (u16*)(W + bw2) + (size_t)l * HH * 2 * HH,
                                             dw2 + (size_t)l * HH * 2 * HH, iflag,
                                             W + pb_o + l * HH, W + pb1 + l * 2 * HH, W + pb2 + l * HH,
                                             gatb, W + pb_gat + l * HH,
                                             W + pbn_g + l * 3 * HH, W + pbn_b + l * 3 * HH,
                                             W + pbn_g + l * 3 * HH + 2 * HH,
                                             W + pbn_b + l * 3 * HH + 2 * HH,
                                             hbuf, hhi, hlo,
                                             W + pw_out, W + pb_out,
                                             (l == LL - 1) ? d_out : nullptr);
    }
}